// Round 9
// baseline (226.016 us; speedup 1.0000x reference)
//
#include <hip/hip_runtime.h>
#include <stdint.h>

#define B_ 8
#define C_ 256
#define N_ 2048
#define HC 128

typedef float f32x4 __attribute__((ext_vector_type(4)));
typedef float f32x16 __attribute__((ext_vector_type(16)));
typedef short s16x8 __attribute__((ext_vector_type(8)));

__device__ __forceinline__ unsigned short f2bf(float f){
  union { float f; unsigned u; } v; v.f = f;
  unsigned r = v.u + 0x7FFF + ((v.u >> 16) & 1u);
  return (unsigned short)(r >> 16);
}
__device__ __forceinline__ float bf2f(unsigned short u){
  union { unsigned u; float f; } v; v.u = ((unsigned)u) << 16;
  return v.f;
}
__device__ __forceinline__ void gload_lds16(const void* g, void* l){
  __builtin_amdgcn_global_load_lds(
      (const __attribute__((address_space(1))) unsigned int*)g,
      (__attribute__((address_space(3))) unsigned int*)l, 16, 0, 0);
}

// ---------------- prep: weights -> bf16, BN affine fold ----------------
struct PrepArgs {
  const float *s0,*s1,*s2,*s3,*s4,*s5;
  unsigned short *d0,*d1,*d2,*d3,*d4,*d5;
  const float *b1,*g1,*be1,*m1,*v1;
  const float *b2,*g2,*be2,*m2,*v2;
  float *sc1,*sh1,*sc2,*sh2;
};

__global__ __launch_bounds__(256) void k_prep(PrepArgs a){
  int gid = blockIdx.x*256 + threadIdx.x;
  const int S0=65536, S1=131072, S2=196608, S3=229376, S4=245760, S5=278528;
  if (gid < S0)      a.d0[gid]    = f2bf(a.s0[gid]);
  else if (gid < S1) a.d1[gid-S0] = f2bf(a.s1[gid-S0]);
  else if (gid < S2) a.d2[gid-S1] = f2bf(a.s2[gid-S1]);
  else if (gid < S3) a.d3[gid-S2] = f2bf(a.s3[gid-S2]);
  else if (gid < S4) a.d4[gid-S3] = f2bf(a.s4[gid-S3]);
  else if (gid < S5) a.d5[gid-S4] = f2bf(a.s5[gid-S4]);
  else if (gid < S5+128){
    int o = gid - S5;
    float inv = a.g1[o] * rsqrtf(a.v1[o] + 1e-5f);
    a.sc1[o] = inv;
    a.sh1[o] = a.b1[o]*inv + a.be1[o] - a.m1[o]*inv;
  } else if (gid < S5+256){
    int o = gid - S5 - 128;
    float inv = a.g2[o] * rsqrtf(a.v2[o] + 1e-5f);
    a.sc2[o] = inv;
    a.sh2[o] = a.b2[o]*inv + a.be2[o] - a.m2[o]*inv;
  }
}

// ---------------- x [B][C][N] f32 -> xn [B][N][C] bf16 ----------------
__global__ __launch_bounds__(256) void k_transpose_x(const float* __restrict__ x,
                                                     unsigned short* __restrict__ xn){
  __shared__ float lds[64][65];
  int b = blockIdx.z, ct = blockIdx.y, nt = blockIdx.x;
  int n0 = nt*64, c0 = ct*64;
  const float* xb = x + (size_t)b*C_*N_;
  int tn = threadIdx.x & 63, tc0 = threadIdx.x >> 6;
  #pragma unroll
  for (int cc = tc0; cc < 64; cc += 4)
    lds[tn][cc] = xb[(size_t)(c0+cc)*N_ + n0 + tn];
  __syncthreads();
  unsigned short* xnb = xn + (size_t)b*N_*C_;
  int cl = threadIdx.x & 63, nl0 = threadIdx.x >> 6;
  #pragma unroll
  for (int nl = nl0; nl < 64; nl += 4)
    xnb[(size_t)(n0+nl)*C_ + c0 + cl] = f2bf(lds[nl][cl]);
}

// ---------------- fused QKV GEMM: stage x-tile once, 3 weight GEMMs ----------------
__global__ __launch_bounds__(256) void k_qkv(
    const unsigned short* __restrict__ xn,
    const unsigned short* __restrict__ wqb, const unsigned short* __restrict__ wkb,
    const unsigned short* __restrict__ wvb,
    const float* __restrict__ bq, const float* __restrict__ bk, const float* __restrict__ bv,
    unsigned short* __restrict__ Qn, unsigned short* __restrict__ Kn,
    unsigned short* __restrict__ Vc)
{
  __shared__ unsigned short Alds[64][256];
  __shared__ unsigned short Tlds[64][260];
  int b = blockIdx.y, nt = blockIdx.x;
  int nb = nt*64;
  const unsigned short* Ab = xn + ((size_t)b*N_ + nb)*C_;
  for (int i = threadIdx.x; i < 64*32; i += 256){
    int r = i >> 5, cv = i & 31;
    *(s16x8*)&Alds[r][(cv*8) ^ ((r&7)<<3)] = *(const s16x8*)&Ab[(size_t)r*C_ + cv*8];
  }
  __syncthreads();
  int w = threadIdx.x >> 6, l = threadIdx.x & 63, lr = l & 15, lq = l >> 4;
  const unsigned short* Ws[3] = {wqb, wkb, wvb};
  const float* bs[3] = {bq, bk, bv};
  f32x4 zero = {0.f,0.f,0.f,0.f};
  for (int z = 0; z < 3; z++){
    const unsigned short* W = Ws[z];
    const float* bias = bs[z];
    f32x4 acc[16];
    #pragma unroll
    for (int i=0;i<16;i++) acc[i] = zero;
    #pragma unroll
    for (int ks = 0; ks < 8; ks++){
      s16x8 a = *(const s16x8*)&Alds[16*w + lr][(32*ks + 8*lq) ^ ((lr&7)<<3)];
      #pragma unroll
      for (int ct = 0; ct < 16; ct++){
        s16x8 bw = *(const s16x8*)&W[(size_t)(16*ct + lr)*C_ + 32*ks + 8*lq];
        acc[ct] = __builtin_amdgcn_mfma_f32_16x16x32_bf16(a, bw, acc[ct], 0, 0, 0);
      }
    }
    if (z < 2){
      unsigned short* ob = (z==0 ? Qn : Kn) + ((size_t)b*N_ + nb)*C_;
      #pragma unroll
      for (int ct = 0; ct < 16; ct++){
        int o = 16*ct + lr;
        float bi = bias[o];
        #pragma unroll
        for (int r = 0; r < 4; r++){
          int row = 16*w + 4*lq + r;
          ob[(size_t)row*C_ + o] = f2bf(acc[ct][r] + bi);
        }
      }
    } else {
      #pragma unroll
      for (int ct = 0; ct < 16; ct++){
        int o = 16*ct + lr;
        float bi = bias[o];
        #pragma unroll
        for (int r = 0; r < 4; r++)
          Tlds[16*w + 4*lq + r][o] = f2bf(acc[ct][r] + bi);
      }
      __syncthreads();
      unsigned short* vb = Vc + (size_t)b*C_*N_;
      int j = threadIdx.x & 63, o0 = threadIdx.x >> 6;
      #pragma unroll
      for (int o = o0; o < 256; o += 4)
        vb[(size_t)o*N_ + nb + j] = Tlds[j][o];
    }
  }
}

// ---------------- attention: 4-wave 32x32 swapped-QK^T, 2 blocks/CU ----------------
// grid 512 x 256 thr = 2 blocks/CU. XCD map: batch b = bid&7. QBLK=128, KVBLK=64,
// m-split 4. Swapped S^T = mfma(K,Q): exp/psum in regs, no P LDS. Single-buffered
// K/V via global_load_lds (inverse-XOR-swizzled source). Epilogue: per-wave LDS
// transpose of the O tile -> s16x8 full-line stores (kills write amplification).
__global__ __launch_bounds__(256, 2) void k_attn(
    const unsigned short* __restrict__ Qn, const unsigned short* __restrict__ Kn,
    const unsigned short* __restrict__ Vc, const float* __restrict__ beta,
    unsigned short* __restrict__ Opb, float* __restrict__ Ls)
{
  __shared__ __align__(16) char smem[65536];
  unsigned short* Klds = (unsigned short*)smem;            // 32 KB
  unsigned short* Vt   = (unsigned short*)(smem + 32768);  // 32 KB
  const int tid = threadIdx.x;
  const int bid = blockIdx.x;
  const int b = bid & 7;
  const int jj = bid >> 3;                  // 0..63
  const int nt = jj & 15, mh = jj >> 4;     // nt 0..15, mh 0..3
  const int nb = nt*128;
  const unsigned short* Qb = Qn + (size_t)b*N_*C_;
  const unsigned short* Kb = Kn + (size_t)b*N_*C_;
  const unsigned short* Vb = Vc + (size_t)b*C_*N_;
  const float* betab = beta + (size_t)b*N_*N_;
  const int w = tid >> 6, lane = tid & 63, q31 = lane & 31, hi = lane >> 5;
  const int qr = nb + 32*w + q31;
  const int wbase = (tid & ~63) * 16;

  // Q B-frags: qf[ks][e] = Q[qr][16*ks + 8*hi + e]  (held whole kernel)
  s16x8 qf[16];
  {
    const unsigned short* qp = Qb + (size_t)qr*C_ + 8*hi;
    #pragma unroll
    for (int ks = 0; ks < 16; ks++)
      qf[ks] = *(const s16x8*)&qp[16*ks];
  }
  f32x16 oacc[8];
  #pragma unroll
  for (int i=0;i<8;i++)
    #pragma unroll
    for (int e=0;e<16;e++) oacc[i][e] = 0.f;
  float psum = 0.f;

// LDS[row][slot] holds K[mb+row][(slot ^ (row&31))*8 .. +8)  (slot = 16B granule)
#define STAGEK(MB) { \
  _Pragma("unroll") \
  for (int rr=0; rr<8; rr++){ \
    const int o_ = rr*4096 + tid*16; \
    const int row_ = o_ >> 9; \
    const int slot_ = (o_ >> 4) & 31; \
    gload_lds16(Kb + (size_t)((MB)+row_)*C_ + ((slot_ ^ (row_&31))<<3), \
                (char*)Klds + rr*4096 + wbase); } }
// LDS[c][slot] holds V[c][(MB) + (slot ^ (c&7))*8 .. +8)
#define STAGEV(MB) { \
  _Pragma("unroll") \
  for (int rr=0; rr<8; rr++){ \
    const int o_ = rr*4096 + tid*16; \
    const int c_ = o_ >> 7; \
    const int slot_ = (o_ >> 4) & 7; \
    gload_lds16(Vb + (size_t)c_*N_ + (MB) + ((slot_ ^ (c_&7))<<3), \
                (char*)Vt + rr*4096 + wbase); } }

  for (int mt = 0; mt < 8; mt++){
    const int mb = mh*512 + mt*64;
    STAGEK(mb)
    STAGEV(mb)
    __syncthreads();           // drains staging; other block computes meanwhile
    #pragma unroll
    for (int a = 0; a < 2; a++){
      // beta: bv[g][e] = beta[qr][mb + 32a + 8g + 4hi + e]
      f32x4 bv[4];
      #pragma unroll
      for (int g=0; g<4; g++)
        bv[g] = *(const f32x4*)&betab[(size_t)qr*N_ + mb + 32*a + 8*g + 4*hi];
      // S^T(m-sub a) = K . Q
      f32x16 sacc;
      #pragma unroll
      for (int e=0;e<16;e++) sacc[e] = 0.f;
      __builtin_amdgcn_s_setprio(1);
      #pragma unroll
      for (int ks=0; ks<16; ks++){
        const s16x8 kf = *(const s16x8*)
            &Klds[(32*a + q31)*256 + (((2*ks + hi) ^ q31) << 3)];
        sacc = __builtin_amdgcn_mfma_f32_32x32x16_bf16(kf, qf[ks], sacc, 0, 0, 0);
      }
      __builtin_amdgcn_s_setprio(0);
      // P = exp(S*beta): lane holds P[q=qr][m = mb+32a + (r&3)+8(r>>2)+4hi]
      float p[16];
      #pragma unroll
      for (int r=0;r<16;r++){
        p[r] = __expf(sacc[r] * bv[r>>2][r&3]);
        psum += p[r];
      }
      // Build PA A-frags via cross-half exchange, then PV
      __builtin_amdgcn_s_setprio(1);
      #pragma unroll
      for (int u=0; u<2; u++){
        unsigned X  = ((unsigned)f2bf(p[8*u+1])<<16) | f2bf(p[8*u+0]);
        unsigned X2 = ((unsigned)f2bf(p[8*u+3])<<16) | f2bf(p[8*u+2]);
        unsigned Y  = ((unsigned)f2bf(p[8*u+5])<<16) | f2bf(p[8*u+4]);
        unsigned Y2 = ((unsigned)f2bf(p[8*u+7])<<16) | f2bf(p[8*u+6]);
        unsigned Xs  = (unsigned)__shfl_xor((int)X,  32, 64);
        unsigned X2s = (unsigned)__shfl_xor((int)X2, 32, 64);
        unsigned Ys  = (unsigned)__shfl_xor((int)Y,  32, 64);
        unsigned Y2s = (unsigned)__shfl_xor((int)Y2, 32, 64);
        union { unsigned uu[4]; s16x8 v; } pa;
        pa.uu[0] = hi ? Ys  : X;
        pa.uu[1] = hi ? Y2s : X2;
        pa.uu[2] = hi ? Y   : Xs;
        pa.uu[3] = hi ? Y2  : X2s;
        const int s = 2*a + u;
        #pragma unroll
        for (int ct=0; ct<8; ct++){
          const int c = 32*ct + q31;
          const s16x8 vf = *(const s16x8*)
              &Vt[c*64 + (((2*s + hi) ^ (c&7)) << 3)];
          oacc[ct] = __builtin_amdgcn_mfma_f32_32x32x16_bf16(pa.v, vf, oacc[ct], 0,0,0);
        }
      }
      __builtin_amdgcn_s_setprio(0);
    }
    __syncthreads();           // all waves done reading LDS before next stage
  }
#undef STAGEK
#undef STAGEV

  // q-row sum: lane and lane^32 cover disjoint m halves of the same q
  psum += __shfl_xor(psum, 32, 64);

  // Epilogue: pack this wave's 32x256 O tile (bf16) into its own 16KB LDS
  // quarter, then stream out as 16B/lane fully-coalesced stores.
  unsigned short* wtile = (unsigned short*)(smem + w*16384);
  #pragma unroll
  for (int ct=0; ct<8; ct++){
    const int c = 32*ct + q31;
    #pragma unroll
    for (int r=0;r<16;r++){
      const int Lr = (r&3) + 8*(r>>2) + 4*hi;   // local q-row 0..31
      wtile[Lr*256 + c] = f2bf(oacc[ct][r]);
    }
  }
  unsigned short* Ob = Opb + ((size_t)mh*8 + b)*(size_t)N_*C_
                     + (size_t)(nb + 32*w)*C_;
  #pragma unroll
  for (int it=0; it<16; it++){
    const int flat = it*64 + lane;
    const int row = flat >> 5, grp = flat & 31;
    s16x8 v = *(const s16x8*)&wtile[row*256 + grp*8];
    *(s16x8*)&Ob[(size_t)row*C_ + grp*8] = v;
  }
  if (hi == 0){
    float* Lb = Ls + ((size_t)mh*8 + b)*N_;
    Lb[qr] = psum;
  }
}

// ---------------- gemm1 with fused 4-way merge + normalize + BN/ReLU ----------------
// out[n][o] = relu( (sum_m Opb[m][n][:] / sum_m Ls[m][n]) @ w1^T * sc + sh )
__global__ __launch_bounds__(256) void k_gemm1m(
    const unsigned short* __restrict__ Opb, const float* __restrict__ Ls,
    const unsigned short* __restrict__ W,
    const float* __restrict__ sc, const float* __restrict__ sh,
    unsigned short* __restrict__ out)
{
  __shared__ unsigned short Alds[64][256];
  int b = blockIdx.y, nt = blockIdx.x, nb = nt*64;
  const size_t PS = (size_t)8*N_*C_;
  for (int i = threadIdx.x; i < 64*32; i += 256){
    int r = i >> 5, cv = i & 31;
    int row = nb + r;
    float ls = Ls[(size_t)b*N_ + row] + Ls[(size_t)(8+b)*N_ + row]
             + Ls[(size_t)(16+b)*N_ + row] + Ls[(size_t)(24+b)*N_ + row];
    float inv = 1.f / ls;
    size_t base = ((size_t)b*N_ + row)*C_ + cv*8;
    float a8[8] = {0.f,0.f,0.f,0.f,0.f,0.f,0.f,0.f};
    #pragma unroll
    for (int m=0;m<4;m++){
      s16x8 v = *(const s16x8*)&Opb[(size_t)m*PS + base];
      #pragma unroll
      for (int j=0;j<8;j++) a8[j] += bf2f((unsigned short)v[j]);
    }
    s16x8 o;
    #pragma unroll
    for (int j=0;j<8;j++) o[j] = (short)f2bf(a8[j] * inv);
    *(s16x8*)&Alds[r][(cv*8) ^ ((r&7)<<3)] = o;
  }
  __syncthreads();
  int w = threadIdx.x >> 6, l = threadIdx.x & 63, lr = l & 15, lq = l >> 4;
  f32x4 acc[8];
  f32x4 zero = {0.f,0.f,0.f,0.f};
  #pragma unroll
  for (int i=0;i<8;i++) acc[i] = zero;
  #pragma unroll
  for (int ks = 0; ks < 8; ks++){
    s16x8 a = *(const s16x8*)&Alds[16*w + lr][(32*ks + 8*lq) ^ ((lr&7)<<3)];
    #pragma unroll
    for (int ct = 0; ct < 8; ct++){
      s16x8 bw = *(const s16x8*)&W[(size_t)(16*ct + lr)*C_ + 32*ks + 8*lq];
      acc[ct] = __builtin_amdgcn_mfma_f32_16x16x32_bf16(a, bw, acc[ct], 0, 0, 0);
    }
  }
  unsigned short* ob = out + ((size_t)b*N_ + nb)*HC;
  #pragma unroll
  for (int ct = 0; ct < 8; ct++){
    int o = 16*ct + lr;
    float s_ = sc[o], h_ = sh[o];
    #pragma unroll
    for (int r = 0; r < 4; r++){
      int row = 16*w + 4*lq + r;
      ob[(size_t)row*HC + o] = f2bf(fmaxf(acc[ct][r]*s_ + h_, 0.f));
    }
  }
}

// ---------------- generic NT GEMM: out[n][o] = epi(sum_c A[n][c] W[o][c]) ----------------
template<int CIN, int COUT, int MODE>
__global__ __launch_bounds__(256) void k_gemm(
    const unsigned short* __restrict__ A, const unsigned short* __restrict__ W,
    const float* __restrict__ bias, const float* __restrict__ sc,
    const float* __restrict__ sh, unsigned short* __restrict__ out)
{
  __shared__ unsigned short Alds[64][CIN];
  int b = blockIdx.y, nt = blockIdx.x, nb = nt*64;
  const unsigned short* Ab = A + ((size_t)b*N_ + nb)*CIN;
  constexpr int PR = CIN/8;
  for (int i = threadIdx.x; i < 64*PR; i += 256){
    int r = i / PR, cv = i % PR;
    *(s16x8*)&Alds[r][(cv*8) ^ ((r&7)<<3)] = *(const s16x8*)&Ab[(size_t)r*CIN + cv*8];
  }
  __syncthreads();
  int w = threadIdx.x >> 6, l = threadIdx.x & 63, lr = l & 15, lq = l >> 4;
  constexpr int NT = COUT/16;
  f32x4 acc[NT];
  f32x4 zero = {0.f,0.f,0.f,0.f};
  #pragma unroll
  for (int i=0;i<NT;i++) acc[i] = zero;
  #pragma unroll
  for (int ks = 0; ks < CIN/32; ks++){
    s16x8 a = *(const s16x8*)&Alds[16*w + lr][(32*ks + 8*lq) ^ ((lr&7)<<3)];
    #pragma unroll
    for (int ct = 0; ct < NT; ct++){
      s16x8 bw = *(const s16x8*)&W[(size_t)(16*ct + lr)*CIN + 32*ks + 8*lq];
      acc[ct] = __builtin_amdgcn_mfma_f32_16x16x32_bf16(a, bw, acc[ct], 0, 0, 0);
    }
  }
  unsigned short* ob = out + ((size_t)b*N_ + nb)*COUT;
  #pragma unroll
  for (int ct = 0; ct < NT; ct++){
    int o = 16*ct + lr;
    float bi = (MODE==0) ? bias[o] : 0.f;
    float s_ = (MODE==1) ? sc[o] : 0.f;
    float h_ = (MODE==1) ? sh[o] : 0.f;
    #pragma unroll
    for (int r = 0; r < 4; r++){
      int row = 16*w + 4*lq + r;
      float y;
      if (MODE==1) y = fmaxf(acc[ct][r]*s_ + h_, 0.f);
      else         y = acc[ct][r] + bi;
      ob[(size_t)row*COUT + o] = f2bf(y);
    }
  }
}

// ---------------- final: out[b][o][n] = x + h2n @ w3^T + b3 ----------------
__global__ __launch_bounds__(256) void k_mlp3(
    const unsigned short* __restrict__ A, const unsigned short* __restrict__ W,
    const float* __restrict__ b3, const float* __restrict__ x,
    float* __restrict__ out)
{
  __shared__ unsigned short Alds[64][128];
  __shared__ float Dlds[64][257];
  int b = blockIdx.y, nt = blockIdx.x, nb = nt*64;
  const unsigned short* Ab = A + ((size_t)b*N_ + nb)*HC;
  for (int i = threadIdx.x; i < 64*16; i += 256){
    int r = i >> 4, cv = i & 15;
    *(s16x8*)&Alds[r][(cv*8) ^ ((r&7)<<3)] = *(const s16x8*)&Ab[(size_t)r*HC + cv*8];
  }
  __syncthreads();
  int w = threadIdx.x >> 6, l = threadIdx.x & 63, lr = l & 15, lq = l >> 4;
  f32x4 acc[16];
  f32x4 zero = {0.f,0.f,0.f,0.f};
  #pragma unroll
  for (int i=0;i<16;i++) acc[i] = zero;
  #pragma unroll
  for (int ks = 0; ks < 4; ks++){
    s16x8 a = *(const s16x8*)&Alds[16*w + lr][(32*ks + 8*lq) ^ ((lr&7)<<3)];
    #pragma unroll
    for (int ct = 0; ct < 16; ct++){
      s16x8 bw = *(const s16x8*)&W[(size_t)(16*ct + lr)*HC + 32*ks + 8*lq];
      acc[ct] = __builtin_amdgcn_mfma_f32_16x16x32_bf16(a, bw, acc[ct], 0, 0, 0);
    }
  }
  #pragma unroll
  for (int ct = 0; ct < 16; ct++){
    int o = 16*ct + lr;
    float bi = b3[o];
    #pragma unroll
    for (int r = 0; r < 4; r++)
      Dlds[16*w + 4*lq + r][o] = acc[ct][r] + bi;
  }
  __syncthreads();
  const float* xb = x + (size_t)b*C_*N_;
  float* ob = out + (size_t)b*C_*N_;
  int j = threadIdx.x & 63, o0 = threadIdx.x >> 6;
  #pragma unroll
  for (int o = o0; o < 256; o += 4)
    ob[(size_t)o*N_ + nb + j] = xb[(size_t)o*N_ + nb + j] + Dlds[j][o];
}

extern "C" void kernel_launch(void* const* d_in, const int* in_sizes, int n_in,
                              void* d_out, int out_size, void* d_ws, size_t ws_size,
                              hipStream_t stream)
{
  const float* x    = (const float*)d_in[0];
  const float* beta = (const float*)d_in[1];
  const float* wq = (const float*)d_in[2];  const float* bq = (const float*)d_in[3];
  const float* wk = (const float*)d_in[4];  const float* bk = (const float*)d_in[5];
  const float* wv = (const float*)d_in[6];  const float* bv = (const float*)d_in[7];
  const float* w1 = (const float*)d_in[8];  const float* b1 = (const float*)d_in[9];
  const float* g1 = (const float*)d_in[10]; const float* be1= (const float*)d_in[11];
  const float* m1 = (const float*)d_in[12]; const float* v1 = (const float*)d_in[13];
  const float* w2 = (const float*)d_in[14]; const float* b2 = (const float*)d_in[15];
  const float* g2 = (const float*)d_in[16]; const float* be2= (const float*)d_in[17];
  const float* m2 = (const float*)d_in[18]; const float* v2 = (const float*)d_in[19];
  const float* w3 = (const float*)d_in[20]; const float* b3 = (const float*)d_in[21];

  char* p = (char*)d_ws;
  auto alloc = [&](size_t n){ char* r = p; p += (n + 255) & ~(size_t)255; return r; };
  unsigned short* xn  = (unsigned short*)alloc((size_t)B_*N_*C_*2);
  unsigned short* Qn  = (unsigned short*)alloc((size_t)B_*N_*C_*2);
  unsigned short* Kn  = (unsigned short*)alloc((size_t)B_*N_*C_*2);
  unsigned short* Vc  = (unsigned short*)alloc((size_t)B_*N_*C_*2);
  unsigned short* h1n = (unsigned short*)alloc((size_t)B_*N_*HC*2);
  unsigned short* h2n = (unsigned short*)alloc((size_t)B_*N_*HC*2);
  unsigned short* Opb = (unsigned short*)alloc((size_t)4*B_*N_*C_*2);
  float* Ls = (float*)alloc((size_t)4*B_*N_*4);
  unsigned short* wqb = (unsigned short*)alloc(65536*2);
  unsigned short* wkb = (unsigned short*)alloc(65536*2);
  unsigned short* wvb = (unsigned short*)alloc(65536*2);
  unsigned short* w1b = (unsigned short*)alloc(32768*2);
  unsigned short* w2b = (unsigned short*)alloc(16384*2);
  unsigned short* w3b = (unsigned short*)alloc(32768*2);
  float* sc1 = (float*)alloc(128*4);
  float* sh1 = (float*)alloc(128*4);
  float* sc2 = (float*)alloc(128*4);
  float* sh2 = (float*)alloc(128*4);

  PrepArgs pa;
  pa.s0 = wq; pa.s1 = wk; pa.s2 = wv; pa.s3 = w1; pa.s4 = w2; pa.s5 = w3;
  pa.d0 = wqb; pa.d1 = wkb; pa.d2 = wvb; pa.d3 = w1b; pa.d4 = w2b; pa.d5 = w3b;
  pa.b1 = b1; pa.g1 = g1; pa.be1 = be1; pa.m1 = m1; pa.v1 = v1;
  pa.b2 = b2; pa.g2 = g2; pa.be2 = be2; pa.m2 = m2; pa.v2 = v2;
  pa.sc1 = sc1; pa.sh1 = sh1; pa.sc2 = sc2; pa.sh2 = sh2;

  k_prep<<<dim3(1089), dim3(256), 0, stream>>>(pa);
  k_transpose_x<<<dim3(32, 4, 8), dim3(256), 0, stream>>>(x, xn);
  k_qkv<<<dim3(32, 8), dim3(256), 0, stream>>>(xn, wqb, wkb, wvb, bq, bk, bv, Qn, Kn, Vc);
  k_attn<<<dim3(512), dim3(256), 0, stream>>>(Qn, Kn, Vc, beta, Opb, Ls);
  k_gemm1m<<<dim3(32, 8), dim3(256), 0, stream>>>(Opb, Ls, w1b, sc1, sh1, h1n);
  k_gemm<128,128,1><<<dim3(32, 8), dim3(256), 0, stream>>>(h1n, w2b, b2, sc2, sh2, h2n);
  k_mlp3<<<dim3(32, 8), dim3(256), 0, stream>>>(h2n, w3b, b3, x, (float*)d_out);
}

// Round 10
// 200.455 us; speedup vs baseline: 1.1275x; 1.1275x over previous
//
#include <hip/hip_runtime.h>
#include <stdint.h>

#define B_ 8
#define C_ 256
#define N_ 2048
#define HC 128

typedef float f32x4 __attribute__((ext_vector_type(4)));
typedef float f32x16 __attribute__((ext_vector_type(16)));
typedef short s16x8 __attribute__((ext_vector_type(8)));

__device__ __forceinline__ unsigned short f2bf(float f){
  union { float f; unsigned u; } v; v.f = f;
  unsigned r = v.u + 0x7FFF + ((v.u >> 16) & 1u);
  return (unsigned short)(r >> 16);
}
__device__ __forceinline__ float bf2f(unsigned short u){
  union { unsigned u; float f; } v; v.u = ((unsigned)u) << 16;
  return v.f;
}
__device__ __forceinline__ void gload_lds16(const void* g, void* l){
  __builtin_amdgcn_global_load_lds(
      (const __attribute__((address_space(1))) unsigned int*)g,
      (__attribute__((address_space(3))) unsigned int*)l, 16, 0, 0);
}

// ---------------- prep: weights -> bf16, BN affine fold ----------------
struct PrepArgs {
  const float *s0,*s1,*s2,*s3,*s4,*s5;
  unsigned short *d0,*d1,*d2,*d3,*d4,*d5;
  const float *b1,*g1,*be1,*m1,*v1;
  const float *b2,*g2,*be2,*m2,*v2;
  float *sc1,*sh1,*sc2,*sh2;
};

__global__ __launch_bounds__(256) void k_prep(PrepArgs a){
  int gid = blockIdx.x*256 + threadIdx.x;
  const int S0=65536, S1=131072, S2=196608, S3=229376, S4=245760, S5=278528;
  if (gid < S0)      a.d0[gid]    = f2bf(a.s0[gid]);
  else if (gid < S1) a.d1[gid-S0] = f2bf(a.s1[gid-S0]);
  else if (gid < S2) a.d2[gid-S1] = f2bf(a.s2[gid-S1]);
  else if (gid < S3) a.d3[gid-S2] = f2bf(a.s3[gid-S2]);
  else if (gid < S4) a.d4[gid-S3] = f2bf(a.s4[gid-S3]);
  else if (gid < S5) a.d5[gid-S4] = f2bf(a.s5[gid-S4]);
  else if (gid < S5+128){
    int o = gid - S5;
    float inv = a.g1[o] * rsqrtf(a.v1[o] + 1e-5f);
    a.sc1[o] = inv;
    a.sh1[o] = a.b1[o]*inv + a.be1[o] - a.m1[o]*inv;
  } else if (gid < S5+256){
    int o = gid - S5 - 128;
    float inv = a.g2[o] * rsqrtf(a.v2[o] + 1e-5f);
    a.sc2[o] = inv;
    a.sh2[o] = a.b2[o]*inv + a.be2[o] - a.m2[o]*inv;
  }
}

// ---------------- x [B][C][N] f32 -> xn [B][N][C] bf16 ----------------
__global__ __launch_bounds__(256) void k_transpose_x(const float* __restrict__ x,
                                                     unsigned short* __restrict__ xn){
  __shared__ float lds[64][65];
  int b = blockIdx.z, ct = blockIdx.y, nt = blockIdx.x;
  int n0 = nt*64, c0 = ct*64;
  const float* xb = x + (size_t)b*C_*N_;
  int tn = threadIdx.x & 63, tc0 = threadIdx.x >> 6;
  #pragma unroll
  for (int cc = tc0; cc < 64; cc += 4)
    lds[tn][cc] = xb[(size_t)(c0+cc)*N_ + n0 + tn];
  __syncthreads();
  unsigned short* xnb = xn + (size_t)b*N_*C_;
  int cl = threadIdx.x & 63, nl0 = threadIdx.x >> 6;
  #pragma unroll
  for (int nl = nl0; nl < 64; nl += 4)
    xnb[(size_t)(n0+nl)*C_ + c0 + cl] = f2bf(lds[nl][cl]);
}

// ---------------- fused QKV GEMM: stage x-tile once, 3 weight GEMMs ----------------
__global__ __launch_bounds__(256) void k_qkv(
    const unsigned short* __restrict__ xn,
    const unsigned short* __restrict__ wqb, const unsigned short* __restrict__ wkb,
    const unsigned short* __restrict__ wvb,
    const float* __restrict__ bq, const float* __restrict__ bk, const float* __restrict__ bv,
    unsigned short* __restrict__ Qn, unsigned short* __restrict__ Kn,
    unsigned short* __restrict__ Vc)
{
  __shared__ unsigned short Alds[64][256];
  __shared__ unsigned short Tlds[64][260];
  int b = blockIdx.y, nt = blockIdx.x;
  int nb = nt*64;
  const unsigned short* Ab = xn + ((size_t)b*N_ + nb)*C_;
  for (int i = threadIdx.x; i < 64*32; i += 256){
    int r = i >> 5, cv = i & 31;
    *(s16x8*)&Alds[r][(cv*8) ^ ((r&7)<<3)] = *(const s16x8*)&Ab[(size_t)r*C_ + cv*8];
  }
  __syncthreads();
  int w = threadIdx.x >> 6, l = threadIdx.x & 63, lr = l & 15, lq = l >> 4;
  const unsigned short* Ws[3] = {wqb, wkb, wvb};
  const float* bs[3] = {bq, bk, bv};
  f32x4 zero = {0.f,0.f,0.f,0.f};
  for (int z = 0; z < 3; z++){
    const unsigned short* W = Ws[z];
    const float* bias = bs[z];
    f32x4 acc[16];
    #pragma unroll
    for (int i=0;i<16;i++) acc[i] = zero;
    #pragma unroll
    for (int ks = 0; ks < 8; ks++){
      s16x8 a = *(const s16x8*)&Alds[16*w + lr][(32*ks + 8*lq) ^ ((lr&7)<<3)];
      #pragma unroll
      for (int ct = 0; ct < 16; ct++){
        s16x8 bw = *(const s16x8*)&W[(size_t)(16*ct + lr)*C_ + 32*ks + 8*lq];
        acc[ct] = __builtin_amdgcn_mfma_f32_16x16x32_bf16(a, bw, acc[ct], 0, 0, 0);
      }
    }
    if (z < 2){
      unsigned short* ob = (z==0 ? Qn : Kn) + ((size_t)b*N_ + nb)*C_;
      #pragma unroll
      for (int ct = 0; ct < 16; ct++){
        int o = 16*ct + lr;
        float bi = bias[o];
        #pragma unroll
        for (int r = 0; r < 4; r++){
          int row = 16*w + 4*lq + r;
          ob[(size_t)row*C_ + o] = f2bf(acc[ct][r] + bi);
        }
      }
    } else {
      #pragma unroll
      for (int ct = 0; ct < 16; ct++){
        int o = 16*ct + lr;
        float bi = bias[o];
        #pragma unroll
        for (int r = 0; r < 4; r++)
          Tlds[16*w + 4*lq + r][o] = f2bf(acc[ct][r] + bi);
      }
      __syncthreads();
      unsigned short* vb = Vc + (size_t)b*C_*N_;
      int j = threadIdx.x & 63, o0 = threadIdx.x >> 6;
      #pragma unroll
      for (int o = o0; o < 256; o += 4)
        vb[(size_t)o*N_ + nb + j] = Tlds[j][o];
    }
  }
}

// ---------------- attention: swapped-QK^T 32x32, beta via async LDS dbuf ----------------
// grid 512 x 256 thr = 2 blocks/CU. XCD map: batch b = bid&7. QBLK=128 (4 waves x
// 32 q), KVBLK=32, m-split 4 (16 tiles/block). beta is staged through
// global_load_lds into a double-buffered LDS tile, ISSUED ONE TILE AHEAD so the
// HBM latency hides under a full tile of compute (the JIT register loads that
// capped every prior round at ~1.2 TB/s are gone). K/V single-buffered (L2-hot).
// Barrier A: lgkmcnt(0)+s_barrier (does NOT drain the beta prefetch); then stage
// K/V(t+1); barrier B: __syncthreads() drains KV + the already-flown beta.
__global__ __launch_bounds__(256, 2) void k_attn(
    const unsigned short* __restrict__ Qn, const unsigned short* __restrict__ Kn,
    const unsigned short* __restrict__ Vc, const float* __restrict__ beta,
    unsigned short* __restrict__ Opb, float* __restrict__ Ls)
{
  __shared__ __align__(16) char smem[65536];
  unsigned short* Klds = (unsigned short*)smem;             // 16 KB  [32 r][256 c]
  unsigned short* Vt   = (unsigned short*)(smem + 16384);   // 16 KB  [256 c][32 m]
  float*          Bl   = (float*)(smem + 32768);            // 2x16KB [128 q][32 m]
  const int tid = threadIdx.x;
  const int bid = blockIdx.x;
  const int b = bid & 7;
  const int jj = bid >> 3;                  // 0..63
  const int nt = jj & 15, mh = jj >> 4;     // nt 0..15, mh 0..3
  const int nb = nt*128;
  const unsigned short* Qb = Qn + (size_t)b*N_*C_;
  const unsigned short* Kb = Kn + (size_t)b*N_*C_;
  const unsigned short* Vb = Vc + (size_t)b*C_*N_;
  const float* betab = beta + (size_t)b*N_*N_;
  const int w = tid >> 6, lane = tid & 63, q31 = lane & 31, hi = lane >> 5;
  const int qr = nb + 32*w + q31;
  const int wbase = (tid & ~63) * 16;

  // Q B-frags: qf[ks][e] = Q[qr][16*ks + 8*hi + e]  (held whole kernel)
  s16x8 qf[16];
  {
    const unsigned short* qp = Qb + (size_t)qr*C_ + 8*hi;
    #pragma unroll
    for (int ks = 0; ks < 16; ks++)
      qf[ks] = *(const s16x8*)&qp[16*ks];
  }
  f32x16 oacc[8];
  #pragma unroll
  for (int i=0;i<8;i++)
    #pragma unroll
    for (int e=0;e<16;e++) oacc[i][e] = 0.f;
  float psum = 0.f;

// K: LDS[row][slot] = K[mb+row][(slot^row)*8 .. +8)   (32 rows x 32 slots)
#define STAGEK(MB) { \
  _Pragma("unroll") \
  for (int rr=0; rr<4; rr++){ \
    const int o_ = rr*4096 + tid*16; \
    const int row_ = o_ >> 9; \
    const int slot_ = (o_ >> 4) & 31; \
    gload_lds16(Kb + (size_t)((MB)+row_)*C_ + ((slot_ ^ (row_&31))<<3), \
                (char*)Klds + rr*4096 + wbase); } }
// V: LDS[c][slot] = V[c][(MB) + (slot^(c&3))*8 .. +8)   (256 c x 4 slots)
#define STAGEV(MB) { \
  _Pragma("unroll") \
  for (int rr=0; rr<4; rr++){ \
    const int o_ = rr*4096 + tid*16; \
    const int c_ = o_ >> 6; \
    const int slot_ = (o_ >> 4) & 3; \
    gload_lds16(Vb + (size_t)c_*N_ + (MB) + ((slot_ ^ (c_&3))<<3), \
                (char*)Vt + rr*4096 + wbase); } }
// beta: LDS buf[q][g] = beta[nb+q][(MB) + (g^(q&7))*4 .. +4)   (128 q x 8 granules)
#define STAGEB(BUF, MB) { \
  _Pragma("unroll") \
  for (int rr=0; rr<4; rr++){ \
    const int o_ = rr*4096 + tid*16; \
    const int row_ = o_ >> 7; \
    const int g_ = (o_ >> 4) & 7; \
    gload_lds16(betab + (size_t)(nb+row_)*N_ + (MB) + ((g_ ^ (row_&7))<<2), \
                (char*)Bl + (BUF)*16384 + rr*4096 + wbase); } }

  // prologue: stage tile 0 (K, V, beta->buf0), full drain
  STAGEK(mh*512)
  STAGEV(mh*512)
  STAGEB(0, mh*512)
  __syncthreads();

  for (int mt = 0; mt < 16; mt++){
    const int mb = mh*512 + mt*32;
    // issue NEXT tile's beta into the alternate buffer (flies under compute)
    if (mt + 1 < 16){
      STAGEB((mt+1)&1, mb+32)
    }
    // beta for this tile from LDS (4-way conflict max via granule^q swizzle)
    const float* Bp = Bl + (mt&1)*4096;
    f32x4 bv[4];
    #pragma unroll
    for (int j=0;j<4;j++)
      bv[j] = *(const f32x4*)&Bp[(32*w + q31)*32 + (((2*j+hi) ^ (q31&7))<<2)];
    // S^T = K . Q   (A = K rows = m-local, B = Q cols = q)
    f32x16 sacc;
    #pragma unroll
    for (int e=0;e<16;e++) sacc[e] = 0.f;
    __builtin_amdgcn_s_setprio(1);
    #pragma unroll
    for (int ks=0; ks<16; ks++){
      const s16x8 kf = *(const s16x8*)
          &Klds[q31*256 + (((2*ks + hi) ^ q31) << 3)];
      sacc = __builtin_amdgcn_mfma_f32_32x32x16_bf16(kf, qf[ks], sacc, 0, 0, 0);
    }
    __builtin_amdgcn_s_setprio(0);
    // P = exp(S*beta): lane holds P[q=qr][m = mb + (r&3)+8(r>>2)+4hi]
    float p[16];
    #pragma unroll
    for (int r=0;r<16;r++){
      p[r] = __expf(sacc[r] * bv[r>>2][r&3]);
      psum += p[r];
    }
    // Build PA A-frags via cross-half exchange, then PV
    __builtin_amdgcn_s_setprio(1);
    #pragma unroll
    for (int u=0; u<2; u++){
      unsigned X  = ((unsigned)f2bf(p[8*u+1])<<16) | f2bf(p[8*u+0]);
      unsigned X2 = ((unsigned)f2bf(p[8*u+3])<<16) | f2bf(p[8*u+2]);
      unsigned Y  = ((unsigned)f2bf(p[8*u+5])<<16) | f2bf(p[8*u+4]);
      unsigned Y2 = ((unsigned)f2bf(p[8*u+7])<<16) | f2bf(p[8*u+6]);
      unsigned Xs  = (unsigned)__shfl_xor((int)X,  32, 64);
      unsigned X2s = (unsigned)__shfl_xor((int)X2, 32, 64);
      unsigned Ys  = (unsigned)__shfl_xor((int)Y,  32, 64);
      unsigned Y2s = (unsigned)__shfl_xor((int)Y2, 32, 64);
      union { unsigned uu[4]; s16x8 v; } pa;
      pa.uu[0] = hi ? Ys  : X;
      pa.uu[1] = hi ? Y2s : X2;
      pa.uu[2] = hi ? Y   : Xs;
      pa.uu[3] = hi ? Y2  : X2s;
      #pragma unroll
      for (int ct=0; ct<8; ct++){
        const int c = 32*ct + q31;
        const s16x8 vf = *(const s16x8*)
            &Vt[c*32 + (((2*u + hi) ^ (c&3)) << 3)];
        oacc[ct] = __builtin_amdgcn_mfma_f32_32x32x16_bf16(pa.v, vf, oacc[ct], 0,0,0);
      }
    }
    __builtin_amdgcn_s_setprio(0);
    // barrier A: LDS reads done; do NOT drain the in-flight beta prefetch
    asm volatile("s_waitcnt lgkmcnt(0)" ::: "memory");
    __builtin_amdgcn_s_barrier();
    // stage next K/V (L2-hot, short latency), then full drain
    if (mt + 1 < 16){
      STAGEK(mb+32)
      STAGEV(mb+32)
    }
    __syncthreads();   // drains KV(t+1) + already-arrived beta(t+1)
  }
#undef STAGEK
#undef STAGEV
#undef STAGEB

  // q-row sum: lane and lane^32 cover disjoint m halves of the same q
  psum += __shfl_xor(psum, 32, 64);
  // store unnormalized bf16 partials (D layout: col=c=q31, row=crow(r,hi)=q)
  unsigned short* Ob = Opb + ((size_t)mh*8 + b)*(size_t)N_*C_;
  #pragma unroll
  for (int ct=0; ct<8; ct++){
    const int c = 32*ct + q31;
    #pragma unroll
    for (int r=0;r<16;r++){
      const int qo = nb + 32*w + (r&3) + 8*(r>>2) + 4*hi;
      Ob[(size_t)qo*C_ + c] = f2bf(oacc[ct][r]);
    }
  }
  if (hi == 0){
    float* Lb = Ls + ((size_t)mh*8 + b)*N_;
    Lb[qr] = psum;
  }
}

// ---------------- gemm1 with fused 4-way merge + normalize + BN/ReLU ----------------
__global__ __launch_bounds__(256) void k_gemm1m(
    const unsigned short* __restrict__ Opb, const float* __restrict__ Ls,
    const unsigned short* __restrict__ W,
    const float* __restrict__ sc, const float* __restrict__ sh,
    unsigned short* __restrict__ out)
{
  __shared__ unsigned short Alds[64][256];
  int b = blockIdx.y, nt = blockIdx.x, nb = nt*64;
  const size_t PS = (size_t)8*N_*C_;
  for (int i = threadIdx.x; i < 64*32; i += 256){
    int r = i >> 5, cv = i & 31;
    int row = nb + r;
    float ls = Ls[(size_t)b*N_ + row] + Ls[(size_t)(8+b)*N_ + row]
             + Ls[(size_t)(16+b)*N_ + row] + Ls[(size_t)(24+b)*N_ + row];
    float inv = 1.f / ls;
    size_t base = ((size_t)b*N_ + row)*C_ + cv*8;
    float a8[8] = {0.f,0.f,0.f,0.f,0.f,0.f,0.f,0.f};
    #pragma unroll
    for (int m=0;m<4;m++){
      s16x8 v = *(const s16x8*)&Opb[(size_t)m*PS + base];
      #pragma unroll
      for (int j=0;j<8;j++) a8[j] += bf2f((unsigned short)v[j]);
    }
    s16x8 o;
    #pragma unroll
    for (int j=0;j<8;j++) o[j] = (short)f2bf(a8[j] * inv);
    *(s16x8*)&Alds[r][(cv*8) ^ ((r&7)<<3)] = o;
  }
  __syncthreads();
  int w = threadIdx.x >> 6, l = threadIdx.x & 63, lr = l & 15, lq = l >> 4;
  f32x4 acc[8];
  f32x4 zero = {0.f,0.f,0.f,0.f};
  #pragma unroll
  for (int i=0;i<8;i++) acc[i] = zero;
  #pragma unroll
  for (int ks = 0; ks < 8; ks++){
    s16x8 a = *(const s16x8*)&Alds[16*w + lr][(32*ks + 8*lq) ^ ((lr&7)<<3)];
    #pragma unroll
    for (int ct = 0; ct < 8; ct++){
      s16x8 bw = *(const s16x8*)&W[(size_t)(16*ct + lr)*C_ + 32*ks + 8*lq];
      acc[ct] = __builtin_amdgcn_mfma_f32_16x16x32_bf16(a, bw, acc[ct], 0, 0, 0);
    }
  }
  unsigned short* ob = out + ((size_t)b*N_ + nb)*HC;
  #pragma unroll
  for (int ct = 0; ct < 8; ct++){
    int o = 16*ct + lr;
    float s_ = sc[o], h_ = sh[o];
    #pragma unroll
    for (int r = 0; r < 4; r++){
      int row = 16*w + 4*lq + r;
      ob[(size_t)row*HC + o] = f2bf(fmaxf(acc[ct][r]*s_ + h_, 0.f));
    }
  }
}

// ---------------- generic NT GEMM: out[n][o] = epi(sum_c A[n][c] W[o][c]) ----------------
template<int CIN, int COUT, int MODE>
__global__ __launch_bounds__(256) void k_gemm(
    const unsigned short* __restrict__ A, const unsigned short* __restrict__ W,
    const float* __restrict__ bias, const float* __restrict__ sc,
    const float* __restrict__ sh, unsigned short* __restrict__ out)
{
  __shared__ unsigned short Alds[64][CIN];
  int b = blockIdx.y, nt = blockIdx.x, nb = nt*64;
  const unsigned short* Ab = A + ((size_t)b*N_ + nb)*CIN;
  constexpr int PR = CIN/8;
  for (int i = threadIdx.x; i < 64*PR; i += 256){
    int r = i / PR, cv = i % PR;
    *(s16x8*)&Alds[r][(cv*8) ^ ((r&7)<<3)] = *(const s16x8*)&Ab[(size_t)r*CIN + cv*8];
  }
  __syncthreads();
  int w = threadIdx.x >> 6, l = threadIdx.x & 63, lr = l & 15, lq = l >> 4;
  constexpr int NT = COUT/16;
  f32x4 acc[NT];
  f32x4 zero = {0.f,0.f,0.f,0.f};
  #pragma unroll
  for (int i=0;i<NT;i++) acc[i] = zero;
  #pragma unroll
  for (int ks = 0; ks < CIN/32; ks++){
    s16x8 a = *(const s16x8*)&Alds[16*w + lr][(32*ks + 8*lq) ^ ((lr&7)<<3)];
    #pragma unroll
    for (int ct = 0; ct < NT; ct++){
      s16x8 bw = *(const s16x8*)&W[(size_t)(16*ct + lr)*CIN + 32*ks + 8*lq];
      acc[ct] = __builtin_amdgcn_mfma_f32_16x16x32_bf16(a, bw, acc[ct], 0, 0, 0);
    }
  }
  unsigned short* ob = out + ((size_t)b*N_ + nb)*COUT;
  #pragma unroll
  for (int ct = 0; ct < NT; ct++){
    int o = 16*ct + lr;
    float bi = (MODE==0) ? bias[o] : 0.f;
    float s_ = (MODE==1) ? sc[o] : 0.f;
    float h_ = (MODE==1) ? sh[o] : 0.f;
    #pragma unroll
    for (int r = 0; r < 4; r++){
      int row = 16*w + 4*lq + r;
      float y;
      if (MODE==1) y = fmaxf(acc[ct][r]*s_ + h_, 0.f);
      else         y = acc[ct][r] + bi;
      ob[(size_t)row*COUT + o] = f2bf(y);
    }
  }
}

// ---------------- final: out[b][o][n] = x + h2n @ w3^T + b3 ----------------
__global__ __launch_bounds__(256) void k_mlp3(
    const unsigned short* __restrict__ A, const unsigned short* __restrict__ W,
    const float* __restrict__ b3, const float* __restrict__ x,
    float* __restrict__ out)
{
  __shared__ unsigned short Alds[64][128];
  __shared__ float Dlds[64][257];
  int b = blockIdx.y, nt = blockIdx.x, nb = nt*64;
  const unsigned short* Ab = A + ((size_t)b*N_ + nb)*HC;
  for (int i = threadIdx.x; i < 64*16; i += 256){
    int r = i >> 4, cv = i & 15;
    *(s16x8*)&Alds[r][(cv*8) ^ ((r&7)<<3)] = *(const s16x8*)&Ab[(size_t)r*HC + cv*8];
  }
  __syncthreads();
  int w = threadIdx.x >> 6, l = threadIdx.x & 63, lr = l & 15, lq = l >> 4;
  f32x4 acc[16];
  f32x4 zero = {0.f,0.f,0.f,0.f};
  #pragma unroll
  for (int i=0;i<16;i++) acc[i] = zero;
  #pragma unroll
  for (int ks = 0; ks < 4; ks++){
    s16x8 a = *(const s16x8*)&Alds[16*w + lr][(32*ks + 8*lq) ^ ((lr&7)<<3)];
    #pragma unroll
    for (int ct = 0; ct < 16; ct++){
      s16x8 bw = *(const s16x8*)&W[(size_t)(16*ct + lr)*HC + 32*ks + 8*lq];
      acc[ct] = __builtin_amdgcn_mfma_f32_16x16x32_bf16(a, bw, acc[ct], 0, 0, 0);
    }
  }
  #pragma unroll
  for (int ct = 0; ct < 16; ct++){
    int o = 16*ct + lr;
    float bi = b3[o];
    #pragma unroll
    for (int r = 0; r < 4; r++)
      Dlds[16*w + 4*lq + r][o] = acc[ct][r] + bi;
  }
  __syncthreads();
  const float* xb = x + (size_t)b*C_*N_;
  float* ob = out + (size_t)b*C_*N_;
  int j = threadIdx.x & 63, o0 = threadIdx.x >> 6;
  #pragma unroll
  for (int o = o0; o < 256; o += 4)
    ob[(size_t)o*N_ + nb + j] = xb[(size_t)o*N_ + nb + j] + Dlds[j][o];
}

extern "C" void kernel_launch(void* const* d_in, const int* in_sizes, int n_in,
                              void* d_out, int out_size, void* d_ws, size_t ws_size,
                              hipStream_t stream)
{
  const float* x    = (const float*)d_in[0];
  const float* beta = (const float*)d_in[1];
  const float* wq = (const float*)d_in[2];  const float* bq = (const float*)d_in[3];
  const float* wk = (const float*)d_in[4];  const float* bk = (const float*)d_in[5];
  const float* wv = (const float*)d_in[6];  const float* bv = (const float*)d_in[7];
  const float* w1 = (const float*)d_in[8];  const float* b1 = (const float*)d_in[9];
  const float* g1 = (const float*)d_in[10]; const float* be1= (const float*)d_in[11];
  const float* m1 = (const float*)d_in[12]; const float* v1 = (const float*)d_in[13];
  const float* w2 = (const float*)d_in[14]; const float* b2 = (const float*)d_in[15];
  const float* g2 = (const float*)d_in[16]; const float* be2= (const float*)d_in[17];
  const float* m2 = (const float*)d_in[18]; const float* v2 = (const float*)d_in[19];
  const float* w3 = (const float*)d_in[20]; const float* b3 = (const float*)d_in[21];

  char* p = (char*)d_ws;
  auto alloc = [&](size_t n){ char* r = p; p += (n + 255) & ~(size_t)255; return r; };
  unsigned short* xn  = (unsigned short*)alloc((size_t)B_*N_*C_*2);
  unsigned short* Qn  = (unsigned short*)alloc((size_t)B_*N_*C_*2);
  unsigned short* Kn  = (unsigned short*)alloc((size_t)B_*N_*C_*2);
  unsigned short* Vc  = (unsigned short*)alloc((size_t)B_*N_*C_*2);
  unsigned short* h1n = (unsigned short*)alloc((size_t)B_*N_*HC*2);
  unsigned short* h2n = (unsigned short*)alloc((size_t)B_*N_*HC*2);
  unsigned short* Opb = (unsigned short*)alloc((size_t)4*B_*N_*C_*2);
  float* Ls = (float*)alloc((size_t)4*B_*N_*4);
  unsigned short* wqb = (unsigned short*)alloc(65536*2);
  unsigned short* wkb = (unsigned short*)alloc(65536*2);
  unsigned short* wvb = (unsigned short*)alloc(65536*2);
  unsigned short* w1b = (unsigned short*)alloc(32768*2);
  unsigned short* w2b = (unsigned short*)alloc(16384*2);
  unsigned short* w3b = (unsigned short*)alloc(32768*2);
  float* sc1 = (float*)alloc(128*4);
  float* sh1 = (float*)alloc(128*4);
  float* sc2 = (float*)alloc(128*4);
  float* sh2 = (float*)alloc(128*4);

  PrepArgs pa;
  pa.s0 = wq; pa.s1 = wk; pa.s2 = wv; pa.s3 = w1; pa.s4 = w2; pa.s5 = w3;
  pa.d0 = wqb; pa.d1 = wkb; pa.d2 = wvb; pa.d3 = w1b; pa.d4 = w2b; pa.d5 = w3b;
  pa.b1 = b1; pa.g1 = g1; pa.be1 = be1; pa.m1 = m1; pa.v1 = v1;
  pa.b2 = b2; pa.g2 = g2; pa.be2 = be2; pa.m2 = m2; pa.v2 = v2;
  pa.sc1 = sc1; pa.sh1 = sh1; pa.sc2 = sc2; pa.sh2 = sh2;

  k_prep<<<dim3(1089), dim3(256), 0, stream>>>(pa);
  k_transpose_x<<<dim3(32, 4, 8), dim3(256), 0, stream>>>(x, xn);
  k_qkv<<<dim3(32, 8), dim3(256), 0, stream>>>(xn, wqb, wkb, wvb, bq, bk, bv, Qn, Kn, Vc);
  k_attn<<<dim3(512), dim3(256), 0, stream>>>(Qn, Kn, Vc, beta, Opb, Ls);
  k_gemm1m<<<dim3(32, 8), dim3(256), 0, stream>>>(Opb, Ls, w1b, sc1, sh1, h1n);
  k_gemm<128,128,1><<<dim3(32, 8), dim3(256), 0, stream>>>(h1n, w2b, b2, sc2, sh2, h2n);
  k_mlp3<<<dim3(32, 8), dim3(256), 0, stream>>>(h2n, w3b, b3, x, (float*)d_out);
}